// Round 9
// baseline (2052.344 us; speedup 1.0000x reference)
//
#include <hip/hip_runtime.h>
#include <hip/hip_bf16.h>
#include <stdint.h>

#define M_DIM 8192
#define N_DIM 4096
#define K_DIM 4096
#define BM 256
#define BN 256
#define BK 64
#define NTL 64

typedef __attribute__((ext_vector_type(8)))  short short8;
typedef __attribute__((ext_vector_type(16))) float f32x16;
typedef unsigned short ushort_t;

#define SBAR()   __builtin_amdgcn_s_barrier()
#define LGKM0()  asm volatile("s_waitcnt lgkmcnt(0)")
#define VMF(n)   asm volatile("s_waitcnt vmcnt(" #n ")" ::: "memory")

// ---------- fp32 -> bf16 (RNE) conversion ----------
__device__ __forceinline__ ushort_t f2bf(float f) {
    uint32_t u = __float_as_uint(f);
    uint32_t r = (u + 0x7FFFu + ((u >> 16) & 1u)) >> 16;
    return (ushort_t)r;
}

__global__ void cvt_f32_bf16(const float4* __restrict__ in, ushort* __restrict__ out4, int n4) {
    int i = blockIdx.x * blockDim.x + threadIdx.x;
    if (i < n4) {
        float4 v = in[i];
        ushort_t a = f2bf(v.x), b = f2bf(v.y), c = f2bf(v.z), d = f2bf(v.w);
        uint32_t lo = (uint32_t)a | ((uint32_t)b << 16);
        uint32_t hi = (uint32_t)c | ((uint32_t)d << 16);
        uint2* o = reinterpret_cast<uint2*>(out4);
        o[i] = make_uint2(lo, hi);
    }
}

__device__ __forceinline__ void gload_lds16(const ushort_t* g, void* l) {
    __builtin_amdgcn_global_load_lds(
        (const __attribute__((address_space(1))) unsigned int*)g,
        (__attribute__((address_space(3))) unsigned int*)l,
        16, 0, 0);
}

// ---------- fused GEMM (x @ W^T) + GroupNorm + bias + clamp ----------
// 256x256 tile, BK=64, 512 thr (8 waves 2Mx4N), 2x64KB dbuf, 4 phases/tile,
// stage stagger {Bhi(T+1)@P1, Alo(T+2)@P2, Ahi(T+2)@P3, Blo(T+2)@P4},
// vmcnt(6)@P4 certifies tile T+1. MFMA = 32x32x16.
// launch_bounds(512,1): LDS already caps residency at 1 block/CU (2 waves/
// SIMD); per-SIMD reg pool 2048 allows 512/wave -> relaxing the declared
// occupancy removes the 256-reg cap that caused round-8's scratch spills
// WITHOUT changing actual occupancy.
__global__ __launch_bounds__(512, 1)
void gemm_gn_kernel(const ushort_t* __restrict__ xb,   // [M][K] bf16
                    const ushort_t* __restrict__ wb,   // [N][K] bf16
                    const float*   __restrict__ bias,  // [N]
                    float*         __restrict__ out)   // [M][N]
{
    __shared__ char pool[131072];   // 2 buf x (A-lo 16K | A-hi 16K | B-lo 16K | B-hi 16K)

    const int tid = threadIdx.x;
    const int w   = tid >> 6;          // wave 0..7
    const int l   = tid & 63;
    const int wr  = w >> 2;            // 0..1 (M)
    const int wc  = w & 3;             // 0..3 (N)
    const int l31 = l & 31;
    const int hi  = l >> 5;

    // bijective XCD swizzle (512 blocks = 8*64)
    const int TN = N_DIM / BN;         // 16
    int bid = blockIdx.x;
    bid = (bid & 7) * 64 + (bid >> 3);
    const int brow = (bid / TN) * BM;
    const int bcol = (bid % TN) * BN;

    // ---- staging: half-tile = 128 rows x 128B = 16KB = 512thr x 2 gloads x 16B
    // LDS dest linear; global SOURCE pre-swizzled: slot ^= row&7 (rule #21)
    const int srow8 = tid >> 3;                      // 0..63
    const int sslot = (tid & 7) ^ (srow8 & 7);
    const ushort_t* gA = xb + (size_t)(brow + srow8) * K_DIM + sslot * 8;
    const ushort_t* gB = wb + (size_t)(bcol + srow8) * K_DIM + sslot * 8;
    const size_t ROW64 = (size_t)64 * K_DIM;
    const int w1024 = w * 1024;

    auto STAGE_A = [&](int buf, int half, int kt) {
        const ushort_t* s = gA + (size_t)half * 128 * K_DIM + (size_t)kt * 64;
        char* d = pool + buf * 65536 + half * 16384 + w1024;
        gload_lds16(s,         d);
        gload_lds16(s + ROW64, d + 8192);
    };
    auto STAGE_B = [&](int buf, int half, int kt) {
        const ushort_t* s = gB + (size_t)half * 128 * K_DIM + (size_t)kt * 64;
        char* d = pool + buf * 65536 + 32768 + half * 16384 + w1024;
        gload_lds16(s,         d);
        gload_lds16(s + ROW64, d + 8192);
    };

    // ---- 32x32x16 fragment addressing.
    // A-frag: lane holds A[row = l&31][k = s*16 + (l>>5)*8 + 0..7]
    // LDS byte within row: (s*32 + hi*16) ^ ((l&7)<<4)  (row&7 == l&7)
    const int swz = (l & 7) << 4;
    int xoff[4];
#pragma unroll
    for (int s = 0; s < 4; ++s) xoff[s] = (s * 32 + hi * 16) ^ swz;

    // m-frag mi in 0..3 -> tile rows mi*64 + wr*32 + (l&31)   (mi 0-1 = A-lo, 2-3 = A-hi)
    // n-frag ni in 0..1 -> tile cols ni*128 + wc*32 + (l&31)  (ni 0 = B-lo = group0)
    short8 afL[8], afH[8], bfL[4], bfH[4];   // af: [mloc*4+s], bf: [s]

    auto RD_A = [&](short8* dst, const char* base, int mi0) {
#pragma unroll
        for (int m = 0; m < 2; ++m) {
            const char* p = base + ((mi0 + m) * 64 + wr * 32 + l31) * 128;
#pragma unroll
            for (int s = 0; s < 4; ++s)
                dst[m * 4 + s] = *(const short8*)(p + xoff[s]);
        }
    };
    auto RD_B = [&](short8* dst, const char* base, int ni) {
        const char* p = base + (ni * 128 + wc * 32 + l31) * 128;
#pragma unroll
        for (int s = 0; s < 4; ++s)
            dst[s] = *(const short8*)(p + xoff[s]);
    };

    f32x16 acc[4][2];
#pragma unroll
    for (int i = 0; i < 4; ++i)
#pragma unroll
        for (int j = 0; j < 2; ++j) acc[i][j] = (f32x16)(0.f);

    auto MM = [&](short8* A, short8* B, int m0, int n) {
        __builtin_amdgcn_s_setprio(1);
#pragma unroll
        for (int s = 0; s < 4; ++s)
#pragma unroll
            for (int m = 0; m < 2; ++m)
                acc[m0 + m][n] = __builtin_amdgcn_mfma_f32_32x32x16_bf16(
                    A[m * 4 + s], B[s], acc[m0 + m][n], 0, 0, 0);
        __builtin_amdgcn_s_setprio(0);
    };

    // ---- prologue: tile0 all 4 halves + tile1 {Alo,Ahi,Blo}; vmcnt(6) -> tile0 ready
    STAGE_A(0, 0, 0); STAGE_A(0, 1, 0);
    STAGE_B(0, 0, 0); STAGE_B(0, 1, 0);
    STAGE_A(1, 0, 1); STAGE_A(1, 1, 1);
    STAGE_B(1, 0, 1);
    VMF(6);
    SBAR();
    RD_A(afL, pool, 0);            // Q1(T0) operands (steady state: read at P4 of T-1)
    RD_B(bfL, pool + 32768, 0);

#pragma unroll 2
    for (int T = 0; T < NTL; ++T) {
        const int c = T & 1;
        const char* Ab = pool + c * 65536;
        const char* Bb = Ab + 32768;
        const char* Abn = pool + (c ^ 1) * 65536;   // tile T+1
        const char* Bbn = Abn + 32768;

        // P1: Q1 (m0-1, n0). Operands already in flight; stage B-hi(T+1).
        if (T + 1 < NTL) STAGE_B(c ^ 1, 1, T + 1);
        SBAR(); LGKM0();
        MM(afL, bfL, 0, 0);
        SBAR();

        // P2: Q2 (m2-3, n0); read afH; stage A-lo(T+2) (safe after P1's closing bar)
        RD_A(afH, Ab, 2);
        if (T + 2 < NTL) STAGE_A(c, 0, T + 2);
        SBAR(); LGKM0();
        MM(afH, bfL, 2, 0);
        SBAR();

        // P3: Q3 (m2-3, n1); read bfH; stage A-hi(T+2)
        RD_B(bfH, Bb, 1);
        if (T + 2 < NTL) STAGE_A(c, 1, T + 2);
        SBAR(); LGKM0();
        MM(afH, bfH, 2, 1);
        SBAR();

        // P4: Q4 (m0-1, n1); stage B-lo(T+2); counted vmcnt certifies tile T+1;
        // then Q1(T+1) reads issue under Q4's MFMA drain.
        if (T + 2 < NTL) STAGE_B(c, 0, T + 2);
        if (T < NTL - 2) { VMF(6); } else { VMF(0); }
        SBAR();
        MM(afL, bfH, 0, 1);
        if (T + 1 < NTL) {
            RD_A(afL, Abn, 0);
            RD_B(bfL, Bbn, 0);
        }
        SBAR();
    }

    __syncthreads();

    // ---------- fused GroupNorm epilogue ----------
    // acc[mi][ni][r]: row = mi*64 + wr*32 + (r&3) + 8*(r>>2) + 4*hi, col = ni*128 + wc*32 + l31
    // group = ni (cols 0-127 vs 128-255)
    float* redS  = (float*)pool;            // [256][4wc][2g] = 8 KB
    float* redS2 = (float*)(pool + 8192);   // 8 KB
    float* minv  = (float*)(pool + 16384);  // [256][4] = 4 KB

#pragma unroll
    for (int mi = 0; mi < 4; ++mi)
#pragma unroll
        for (int r = 0; r < 16; ++r) {
            float gl = acc[mi][0][r], gh = acc[mi][1][r];
            float gl2 = gl * gl, gh2 = gh * gh;
#pragma unroll
            for (int m = 1; m < 32; m <<= 1) {
                gl  += __shfl_xor(gl,  m);
                gh  += __shfl_xor(gh,  m);
                gl2 += __shfl_xor(gl2, m);
                gh2 += __shfl_xor(gh2, m);
            }
            if (l31 == 0) {
                int R = mi * 64 + wr * 32 + (r & 3) + 8 * (r >> 2) + 4 * hi;
                redS [R * 8 + wc * 2]     = gl;
                redS [R * 8 + wc * 2 + 1] = gh;
                redS2[R * 8 + wc * 2]     = gl2;
                redS2[R * 8 + wc * 2 + 1] = gh2;
            }
        }
    __syncthreads();

    // per-row mean/inv precompute (256 threads)
    if (tid < 256) {
        const float inv_gs = 1.0f / 128.0f;
        int R = tid;
        float S0 = redS [R * 8 + 0] + redS [R * 8 + 2] + redS [R * 8 + 4] + redS [R * 8 + 6];
        float S1 = redS [R * 8 + 1] + redS [R * 8 + 3] + redS [R * 8 + 5] + redS [R * 8 + 7];
        float T0 = redS2[R * 8 + 0] + redS2[R * 8 + 2] + redS2[R * 8 + 4] + redS2[R * 8 + 6];
        float T1 = redS2[R * 8 + 1] + redS2[R * 8 + 3] + redS2[R * 8 + 5] + redS2[R * 8 + 7];
        float mean0 = S0 * inv_gs, mean1 = S1 * inv_gs;
        minv[R * 4 + 0] = mean0;
        minv[R * 4 + 1] = rsqrtf(T0 * inv_gs - mean0 * mean0 + 1e-6f);
        minv[R * 4 + 2] = mean1;
        minv[R * 4 + 3] = rsqrtf(T1 * inv_gs - mean1 * mean1 + 1e-6f);
    }
    __syncthreads();

    float bv0 = bias[bcol + wc * 32 + l31];
    float bv1 = bias[bcol + 128 + wc * 32 + l31];

#pragma unroll
    for (int mi = 0; mi < 4; ++mi)
#pragma unroll
        for (int r = 0; r < 16; ++r) {
            int R = mi * 64 + wr * 32 + (r & 3) + 8 * (r >> 2) + 4 * hi;
            float4 mv = *(const float4*)&minv[R * 4];
            size_t rowbase = (size_t)(brow + R) * N_DIM + bcol + wc * 32 + l31;
            float v0 = (acc[mi][0][r] - mv.x) * mv.y + bv0;
            float v1 = (acc[mi][1][r] - mv.z) * mv.w + bv1;
            v0 = fminf(fmaxf(v0, -2.0f), 2.0f);
            v1 = fminf(fmaxf(v1, -2.0f), 2.0f);
            out[rowbase]       = v0;
            out[rowbase + 128] = v1;
        }
}

extern "C" void kernel_launch(void* const* d_in, const int* in_sizes, int n_in,
                              void* d_out, int out_size, void* d_ws, size_t ws_size,
                              hipStream_t stream) {
    const float* x = (const float*)d_in[0];
    const float* W = (const float*)d_in[1];
    const float* b = (const float*)d_in[2];
    float* out = (float*)d_out;

    ushort_t* xb = (ushort_t*)d_ws;                       // 64 MB
    ushort_t* wb = xb + (size_t)M_DIM * K_DIM;            // +32 MB

    int n4x = M_DIM * K_DIM / 4;
    cvt_f32_bf16<<<(n4x + 255) / 256, 256, 0, stream>>>(
        (const float4*)x, xb, n4x);
    int n4w = N_DIM * K_DIM / 4;
    cvt_f32_bf16<<<(n4w + 255) / 256, 256, 0, stream>>>(
        (const float4*)W, wb, n4w);

    int grid = (M_DIM / BM) * (N_DIM / BN);               // 512 blocks
    gemm_gn_kernel<<<grid, 512, 0, stream>>>(xb, wb, b, out);
}

// Round 11
// 320.346 us; speedup vs baseline: 6.4066x; 6.4066x over previous
//
#include <hip/hip_runtime.h>
#include <hip/hip_bf16.h>
#include <stdint.h>

#define M_DIM 8192
#define N_DIM 4096
#define K_DIM 4096
#define BM 256
#define BN 256
#define NSTEP 128          // K-32 pipeline steps
#define NT64 64            // K-64 storage tiles

typedef __attribute__((ext_vector_type(8))) short short8;
typedef __attribute__((ext_vector_type(4))) float f32x4;
typedef unsigned short ushort_t;

#define SBAR()    __builtin_amdgcn_s_barrier()
#define SCHEDB()  __builtin_amdgcn_sched_barrier(0)
#define LGKM0M()  asm volatile("s_waitcnt lgkmcnt(0)" ::: "memory")
#define VMF(n)    asm volatile("s_waitcnt vmcnt(" #n ")" ::: "memory")

// ---------- fp32 -> bf16 (RNE) conversion ----------
__device__ __forceinline__ ushort_t f2bf(float f) {
    uint32_t u = __float_as_uint(f);
    uint32_t r = (u + 0x7FFFu + ((u >> 16) & 1u)) >> 16;
    return (ushort_t)r;
}

__global__ void cvt_f32_bf16(const float4* __restrict__ in, ushort* __restrict__ out4, int n4) {
    int i = blockIdx.x * blockDim.x + threadIdx.x;
    if (i < n4) {
        float4 v = in[i];
        ushort_t a = f2bf(v.x), b = f2bf(v.y), c = f2bf(v.z), d = f2bf(v.w);
        uint32_t lo = (uint32_t)a | ((uint32_t)b << 16);
        uint32_t hi = (uint32_t)c | ((uint32_t)d << 16);
        uint2* o = reinterpret_cast<uint2*>(out4);
        o[i] = make_uint2(lo, hi);
    }
}

__device__ __forceinline__ void gload_lds16(const ushort_t* g, void* l) {
    __builtin_amdgcn_global_load_lds(
        (const __attribute__((address_space(1))) unsigned int*)g,
        (__attribute__((address_space(3))) unsigned int*)l,
        16, 0, 0);
}

// ---------- fused GEMM (x @ W^T) + GroupNorm + bias + clamp ----------
// K-32 pipeline, K-64 storage tiles, 2x64KB dbuf. Step u:
//   [lgkm0 (my reads(u) retired) ; VMF(0) at even u (drains tile staged u-1);
//    SBAR (publishes) ; odd u: stage FULL tile (u+3)/2 (8 gloads) ;
//    RDALL(slice u+1 -> other bank) ; 32 MFMA (cur bank)]
// Publication chain: tile t staged@2t-3 -> drained by every wave's VMF(0)
// @head 2t-2 -> published by SBAR@2t-1 -> first read @2t-1 AFTER that SBAR.
// Overwrite: tile t+2 staged @2t+1 post-SBAR; all reads of tile t retired
// via LGKM0@2t+1 pre-SBAR. Same-step stage vs reads: opposite buffers.
// Reads issue BEFORE the MFMA cluster -> LDS pipe (~1150cy/step) drains
// under the MFMA window (~1242cy/SIMD) instead of alternating with it.
__global__ __launch_bounds__(512, 2)
void gemm_gn_kernel(const ushort_t* __restrict__ xb,   // [M][K] bf16
                    const ushort_t* __restrict__ wb,   // [N][K] bf16
                    const float*   __restrict__ bias,  // [N]
                    float*         __restrict__ out)   // [M][N]
{
    __shared__ char pool[131072];   // 2 buf x (A 32K [256r x 128B] + B 32K)

    const int tid = threadIdx.x;
    const int w   = tid >> 6;          // wave 0..7
    const int l   = tid & 63;
    const int wr  = w >> 2;            // 0..1 (M)
    const int wc  = w & 3;             // 0..3 (N)
    const int l15 = l & 15;
    const int l4  = l >> 4;

    // bijective XCD swizzle (512 blocks = 8*64)
    const int TN = N_DIM / BN;         // 16
    int bid = blockIdx.x;
    bid = (bid & 7) * 64 + (bid >> 3);
    const int brow = (bid / TN) * BM;
    const int bcol = (bid % TN) * BN;

    // ---- staging: half-tile = 128 rows x 128B = 16KB = 512thr x 2 gloads x 16B
    // LDS dest linear; global SOURCE pre-swizzled: slot ^= row&7 (rule #21)
    const int srow8 = tid >> 3;                      // 0..63
    const int sslot = (tid & 7) ^ (srow8 & 7);
    const ushort_t* gA = xb + (size_t)(brow + srow8) * K_DIM + sslot * 8;
    const ushort_t* gB = wb + (size_t)(bcol + srow8) * K_DIM + sslot * 8;
    const size_t ROW64 = (size_t)64 * K_DIM;
    const int w1024 = w * 1024;

    auto STAGE_A = [&](int buf, int half, int kt) {
        const ushort_t* s = gA + (size_t)half * 128 * K_DIM + (size_t)kt * 64;
        char* d = pool + buf * 65536 + half * 16384 + w1024;
        gload_lds16(s,         d);
        gload_lds16(s + ROW64, d + 8192);
    };
    auto STAGE_B = [&](int buf, int half, int kt) {
        const ushort_t* s = gB + (size_t)half * 128 * K_DIM + (size_t)kt * 64;
        char* d = pool + buf * 65536 + 32768 + half * 16384 + w1024;
        gload_lds16(s,         d);
        gload_lds16(s + ROW64, d + 8192);
    };

    // fragment read addressing; row&7 == l15&7 matches stage-side swizzle
    const int swz = (l15 & 7) << 4;
    const int abase = (wr * 16 + l15) * 128;
    const int bbase = (wc * 16 + l15) * 128;

    // 12 ds_read_b128 for slice u1 (one K-32 slice of the 8x4 fragment set)
    auto RDALL = [&](short8* af, short8* bf, int u1) {
        const char* base = pool + (((u1 >> 1) & 1) << 16);
        const int xp = ((u1 & 1) * 64 + l4 * 16) ^ swz;
#pragma unroll
        for (int mi = 0; mi < 8; ++mi)
            af[mi] = *(const short8*)(base + abase + mi * 32 * 128 + xp);
        const char* bb = base + 32768;
#pragma unroll
        for (int ni = 0; ni < 4; ++ni)
            bf[ni] = *(const short8*)(bb + bbase + ni * 64 * 128 + xp);
    };

    f32x4 acc[8][4];
#pragma unroll
    for (int i = 0; i < 8; ++i)
#pragma unroll
        for (int j = 0; j < 4; ++j) acc[i][j] = (f32x4){0.f, 0.f, 0.f, 0.f};

    auto STEP = [&](int u, bool vm0, short8* afc, short8* bfc, short8* afn, short8* bfn) {
        LGKM0M();            // my reads(u) [issued step u-1] retired pre-barrier
        if (vm0) { VMF(0); } // even u: drain tile staged at u-1 (full cover >=1242cy)
        SCHEDB();
        SBAR();              // publish stage(u-1) + order WAR regions
        const int ts = (u + 3) >> 1;           // odd u: tile staged this step
        if ((u & 1) && ts < NT64) {
            STAGE_A(ts & 1, 0, ts); STAGE_A(ts & 1, 1, ts);
            STAGE_B(ts & 1, 0, ts); STAGE_B(ts & 1, 1, ts);
        }
        if (u < NSTEP - 1) RDALL(afn, bfn, u + 1);   // reads BEFORE MFMA cluster
        __builtin_amdgcn_s_setprio(1);
#pragma unroll
        for (int mi = 0; mi < 8; ++mi)
#pragma unroll
            for (int ni = 0; ni < 4; ++ni)
                acc[mi][ni] = __builtin_amdgcn_mfma_f32_16x16x32_bf16(
                    afc[mi], bfc[ni], acc[mi][ni], 0, 0, 0);
        __builtin_amdgcn_s_setprio(0);
        SCHEDB();
    };

    // ---- prologue: stage tile0 + tile1 (16 gloads); drain tile0; reads(slice0)
    STAGE_A(0, 0, 0); STAGE_A(0, 1, 0);
    STAGE_B(0, 0, 0); STAGE_B(0, 1, 0);
    STAGE_A(1, 0, 1); STAGE_A(1, 1, 1);
    STAGE_B(1, 0, 1); STAGE_B(1, 1, 1);
    VMF(8);                       // tile0 landed; tile1's 8 in flight
    SBAR();

    short8 afA[8], bfA[4], afB[8], bfB[4];
    RDALL(afA, bfA, 0);
    SCHEDB();

    for (int s = 0; s < NSTEP / 2; ++s) {
        STEP(2 * s,     true,  afA, bfA, afB, bfB);
        STEP(2 * s + 1, false, afB, bfB, afA, bfA);
    }

    __syncthreads();

    // ---------- fused GroupNorm epilogue (verified r5/r7) ----------
    // acc[mi][ni][r]: row = mi*32+wr*16+l4*4+r, col = ni*64+wc*16+l15
    // group 0 = cols 0-127 (ni=0,1), group 1 = cols 128-255 (ni=2,3)
    float* redS  = (float*)pool;            // [256][4wc][2g]
    float* redS2 = (float*)(pool + 8192);
#pragma unroll
    for (int mi = 0; mi < 8; ++mi)
#pragma unroll
        for (int r = 0; r < 4; ++r) {
            float gl  = acc[mi][0][r] + acc[mi][1][r];
            float gh  = acc[mi][2][r] + acc[mi][3][r];
            float gl2 = acc[mi][0][r] * acc[mi][0][r] + acc[mi][1][r] * acc[mi][1][r];
            float gh2 = acc[mi][2][r] * acc[mi][2][r] + acc[mi][3][r] * acc[mi][3][r];
#pragma unroll
            for (int m = 1; m < 16; m <<= 1) {
                gl  += __shfl_xor(gl,  m);
                gh  += __shfl_xor(gh,  m);
                gl2 += __shfl_xor(gl2, m);
                gh2 += __shfl_xor(gh2, m);
            }
            if (l15 == 0) {
                int R = mi * 32 + wr * 16 + l4 * 4 + r;
                redS [R * 8 + wc * 2]     = gl;
                redS [R * 8 + wc * 2 + 1] = gh;
                redS2[R * 8 + wc * 2]     = gl2;
                redS2[R * 8 + wc * 2 + 1] = gh2;
            }
        }
    __syncthreads();

    float bv[4];
#pragma unroll
    for (int ni = 0; ni < 4; ++ni)
        bv[ni] = bias[bcol + ni * 64 + wc * 16 + l15];

    const float inv_gs = 1.0f / 128.0f;
#pragma unroll
    for (int mi = 0; mi < 8; ++mi)
#pragma unroll
        for (int r = 0; r < 4; ++r) {
            int R = mi * 32 + wr * 16 + l4 * 4 + r;
            float S0 = redS [R * 8 + 0] + redS [R * 8 + 2] + redS [R * 8 + 4] + redS [R * 8 + 6];
            float S1 = redS [R * 8 + 1] + redS [R * 8 + 3] + redS [R * 8 + 5] + redS [R * 8 + 7];
            float T0 = redS2[R * 8 + 0] + redS2[R * 8 + 2] + redS2[R * 8 + 4] + redS2[R * 8 + 6];
            float T1 = redS2[R * 8 + 1] + redS2[R * 8 + 3] + redS2[R * 8 + 5] + redS2[R * 8 + 7];
            float mean0 = S0 * inv_gs, mean1 = S1 * inv_gs;
            float inv0 = rsqrtf(T0 * inv_gs - mean0 * mean0 + 1e-6f);
            float inv1 = rsqrtf(T1 * inv_gs - mean1 * mean1 + 1e-6f);
            size_t rowbase = (size_t)(brow + R) * N_DIM + bcol + wc * 16 + l15;
#pragma unroll
            for (int ni = 0; ni < 4; ++ni) {
                float mean = (ni < 2) ? mean0 : mean1;
                float inv  = (ni < 2) ? inv0  : inv1;
                float v = (acc[mi][ni][r] - mean) * inv + bv[ni];
                v = fminf(fmaxf(v, -2.0f), 2.0f);
                out[rowbase + ni * 64] = v;
            }
        }
}

extern "C" void kernel_launch(void* const* d_in, const int* in_sizes, int n_in,
                              void* d_out, int out_size, void* d_ws, size_t ws_size,
                              hipStream_t stream) {
    const float* x = (const float*)d_in[0];
    const float* W = (const float*)d_in[1];
    const float* b = (const float*)d_in[2];
    float* out = (float*)d_out;

    ushort_t* xb = (ushort_t*)d_ws;                       // 64 MB
    ushort_t* wb = xb + (size_t)M_DIM * K_DIM;            // +32 MB

    int n4x = M_DIM * K_DIM / 4;
    cvt_f32_bf16<<<(n4x + 255) / 256, 256, 0, stream>>>(
        (const float4*)x, xb, n4x);
    int n4w = N_DIM * K_DIM / 4;
    cvt_f32_bf16<<<(n4w + 255) / 256, 256, 0, stream>>>(
        (const float4*)W, wb, n4w);

    int grid = (M_DIM / BM) * (N_DIM / BN);               // 512 blocks
    gemm_gn_kernel<<<grid, 512, 0, stream>>>(xb, wb, b, out);
}

// Round 12
// 319.174 us; speedup vs baseline: 6.4302x; 1.0037x over previous
//
#include <hip/hip_runtime.h>
#include <hip/hip_bf16.h>
#include <stdint.h>

#define M_DIM 8192
#define N_DIM 4096
#define K_DIM 4096
#define BM 256
#define BN 256
#define NSTEP 128          // K-32 pipeline steps
#define NT64 64            // K-64 storage tiles

typedef __attribute__((ext_vector_type(8))) short short8;
typedef __attribute__((ext_vector_type(4))) float f32x4;
typedef unsigned short ushort_t;

#define SBAR()    __builtin_amdgcn_s_barrier()
#define SCHEDB()  __builtin_amdgcn_sched_barrier(0)
#define LGKM0M()  asm volatile("s_waitcnt lgkmcnt(0)" ::: "memory")
#define VMF(n)    asm volatile("s_waitcnt vmcnt(" #n ")" ::: "memory")

// ---------- fp32 -> bf16 (RNE) conversion ----------
__device__ __forceinline__ ushort_t f2bf(float f) {
    uint32_t u = __float_as_uint(f);
    uint32_t r = (u + 0x7FFFu + ((u >> 16) & 1u)) >> 16;
    return (ushort_t)r;
}

__global__ void cvt_f32_bf16(const float4* __restrict__ in, ushort* __restrict__ out4, int n4) {
    int i = blockIdx.x * blockDim.x + threadIdx.x;
    if (i < n4) {
        float4 v = in[i];
        ushort_t a = f2bf(v.x), b = f2bf(v.y), c = f2bf(v.z), d = f2bf(v.w);
        uint32_t lo = (uint32_t)a | ((uint32_t)b << 16);
        uint32_t hi = (uint32_t)c | ((uint32_t)d << 16);
        uint2* o = reinterpret_cast<uint2*>(out4);
        o[i] = make_uint2(lo, hi);
    }
}

__device__ __forceinline__ void gload_lds16(const ushort_t* g, void* l) {
    __builtin_amdgcn_global_load_lds(
        (const __attribute__((address_space(1))) unsigned int*)g,
        (__attribute__((address_space(3))) unsigned int*)l,
        16, 0, 0);
}

// ---------- fused GEMM (x @ W^T) + GroupNorm + bias + clamp ----------
// K-32 pipeline, K-64 storage tiles, 2x64KB dbuf. Step u:
//   [lgkm0 ; VMF(0) at even u ; SBAR ; odd u: stage FULL tile (u+3)/2 ;
//    RDALL(slice u+1 -> other bank) ; SCHED_BARRIER ; 32 MFMA (cur bank)]
// The sched_barrier pins the 12 ds_reads ABOVE the MFMA cluster: at the
// 128-VGPR cap the LLVM scheduler otherwise sinks them below it (pressure
// mode), producing CU-wide LDS/MFMA alternation -- the ~36% plateau of
// r3/r5/r7/r11. With the pin, the LDS burst (~1152cy/CU) drains under the
// matrix window (~1242cy/SIMD); next step's lgkm0 is ~free.
// Publication chain (passed r11): tile t staged@2t-3 -> VMF(0)@2t-2 ->
// SBAR@2t-1 publishes -> first read@2t-1 after that SBAR. Overwrite of t
// (stage t+2 @2t+1) is post-SBAR@2t+1; reads of t retired via LGKM0@2t+1.
__global__ __launch_bounds__(512, 2)
void gemm_gn_kernel(const ushort_t* __restrict__ xb,   // [M][K] bf16
                    const ushort_t* __restrict__ wb,   // [N][K] bf16
                    const float*   __restrict__ bias,  // [N]
                    float*         __restrict__ out)   // [M][N]
{
    __shared__ char pool[131072];   // 2 buf x (A 32K [256r x 128B] + B 32K)

    const int tid = threadIdx.x;
    const int w   = tid >> 6;          // wave 0..7
    const int l   = tid & 63;
    const int wr  = w >> 2;            // 0..1 (M)
    const int wc  = w & 3;             // 0..3 (N)
    const int l15 = l & 15;
    const int l4  = l >> 4;

    // bijective XCD swizzle (512 blocks = 8*64)
    const int TN = N_DIM / BN;         // 16
    int bid = blockIdx.x;
    bid = (bid & 7) * 64 + (bid >> 3);
    const int brow = (bid / TN) * BM;
    const int bcol = (bid % TN) * BN;

    // ---- staging: half-tile = 128 rows x 128B = 16KB = 512thr x 2 gloads x 16B
    // LDS dest linear; global SOURCE pre-swizzled: slot ^= row&7 (rule #21)
    const int srow8 = tid >> 3;                      // 0..63
    const int sslot = (tid & 7) ^ (srow8 & 7);
    const ushort_t* gA = xb + (size_t)(brow + srow8) * K_DIM + sslot * 8;
    const ushort_t* gB = wb + (size_t)(bcol + srow8) * K_DIM + sslot * 8;
    const size_t ROW64 = (size_t)64 * K_DIM;
    const int w1024 = w * 1024;

    auto STAGE_A = [&](int buf, int half, int kt) {
        const ushort_t* s = gA + (size_t)half * 128 * K_DIM + (size_t)kt * 64;
        char* d = pool + buf * 65536 + half * 16384 + w1024;
        gload_lds16(s,         d);
        gload_lds16(s + ROW64, d + 8192);
    };
    auto STAGE_B = [&](int buf, int half, int kt) {
        const ushort_t* s = gB + (size_t)half * 128 * K_DIM + (size_t)kt * 64;
        char* d = pool + buf * 65536 + 32768 + half * 16384 + w1024;
        gload_lds16(s,         d);
        gload_lds16(s + ROW64, d + 8192);
    };

    // fragment read addressing; row&7 == l15&7 matches stage-side swizzle
    const int swz = (l15 & 7) << 4;
    const int abase = (wr * 16 + l15) * 128;
    const int bbase = (wc * 16 + l15) * 128;

    // 12 ds_read_b128 for slice u1 (one K-32 slice of the 8x4 fragment set)
    auto RDALL = [&](short8* af, short8* bf, int u1) {
        const char* base = pool + (((u1 >> 1) & 1) << 16);
        const int xp = ((u1 & 1) * 64 + l4 * 16) ^ swz;
#pragma unroll
        for (int mi = 0; mi < 8; ++mi)
            af[mi] = *(const short8*)(base + abase + mi * 32 * 128 + xp);
        const char* bb = base + 32768;
#pragma unroll
        for (int ni = 0; ni < 4; ++ni)
            bf[ni] = *(const short8*)(bb + bbase + ni * 64 * 128 + xp);
    };

    f32x4 acc[8][4];
#pragma unroll
    for (int i = 0; i < 8; ++i)
#pragma unroll
        for (int j = 0; j < 4; ++j) acc[i][j] = (f32x4){0.f, 0.f, 0.f, 0.f};

    auto STEP = [&](int u, bool vm0, short8* afc, short8* bfc, short8* afn, short8* bfn) {
        LGKM0M();            // my reads(u) [issued step u-1] retired pre-barrier
        if (vm0) { VMF(0); } // even u: drain tile staged at u-1
        SCHEDB();
        SBAR();              // publish stage(u-1) + order WAR regions
        const int ts = (u + 3) >> 1;           // odd u: tile staged this step
        if ((u & 1) && ts < NT64) {
            STAGE_A(ts & 1, 0, ts); STAGE_A(ts & 1, 1, ts);
            STAGE_B(ts & 1, 0, ts); STAGE_B(ts & 1, 1, ts);
        }
        if (u < NSTEP - 1) RDALL(afn, bfn, u + 1);   // reads for NEXT step
        SCHEDB();            // *** pin reads/stage ABOVE the MFMA cluster ***
        __builtin_amdgcn_s_setprio(1);
#pragma unroll
        for (int mi = 0; mi < 8; ++mi)
#pragma unroll
            for (int ni = 0; ni < 4; ++ni)
                acc[mi][ni] = __builtin_amdgcn_mfma_f32_16x16x32_bf16(
                    afc[mi], bfc[ni], acc[mi][ni], 0, 0, 0);
        __builtin_amdgcn_s_setprio(0);
        SCHEDB();
    };

    // ---- prologue: stage tile0 + tile1 (16 gloads); drain tile0; reads(slice0)
    STAGE_A(0, 0, 0); STAGE_A(0, 1, 0);
    STAGE_B(0, 0, 0); STAGE_B(0, 1, 0);
    STAGE_A(1, 0, 1); STAGE_A(1, 1, 1);
    STAGE_B(1, 0, 1); STAGE_B(1, 1, 1);
    VMF(8);                       // tile0 landed; tile1's 8 in flight
    SBAR();

    short8 afA[8], bfA[4], afB[8], bfB[4];
    RDALL(afA, bfA, 0);
    SCHEDB();

    for (int s = 0; s < NSTEP / 2; ++s) {
        STEP(2 * s,     true,  afA, bfA, afB, bfB);
        STEP(2 * s + 1, false, afB, bfB, afA, bfA);
    }

    __syncthreads();

    // ---------- fused GroupNorm epilogue (verified r5/r7/r11) ----------
    // acc[mi][ni][r]: row = mi*32+wr*16+l4*4+r, col = ni*64+wc*16+l15
    // group 0 = cols 0-127 (ni=0,1), group 1 = cols 128-255 (ni=2,3)
    float* redS  = (float*)pool;            // [256][4wc][2g]
    float* redS2 = (float*)(pool + 8192);
#pragma unroll
    for (int mi = 0; mi < 8; ++mi)
#pragma unroll
        for (int r = 0; r < 4; ++r) {
            float gl  = acc[mi][0][r] + acc[mi][1][r];
            float gh  = acc[mi][2][r] + acc[mi][3][r];
            float gl2 = acc[mi][0][r] * acc[mi][0][r] + acc[mi][1][r] * acc[mi][1][r];
            float gh2 = acc[mi][2][r] * acc[mi][2][r] + acc[mi][3][r] * acc[mi][3][r];
#pragma unroll
            for (int m = 1; m < 16; m <<= 1) {
                gl  += __shfl_xor(gl,  m);
                gh  += __shfl_xor(gh,  m);
                gl2 += __shfl_xor(gl2, m);
                gh2 += __shfl_xor(gh2, m);
            }
            if (l15 == 0) {
                int R = mi * 32 + wr * 16 + l4 * 4 + r;
                redS [R * 8 + wc * 2]     = gl;
                redS [R * 8 + wc * 2 + 1] = gh;
                redS2[R * 8 + wc * 2]     = gl2;
                redS2[R * 8 + wc * 2 + 1] = gh2;
            }
        }
    __syncthreads();

    float bv[4];
#pragma unroll
    for (int ni = 0; ni < 4; ++ni)
        bv[ni] = bias[bcol + ni * 64 + wc * 16 + l15];

    const float inv_gs = 1.0f / 128.0f;
#pragma unroll
    for (int mi = 0; mi < 8; ++mi)
#pragma unroll
        for (int r = 0; r < 4; ++r) {
            int R = mi * 32 + wr * 16 + l4 * 4 + r;
            float S0 = redS [R * 8 + 0] + redS [R * 8 + 2] + redS [R * 8 + 4] + redS [R * 8 + 6];
            float S1 = redS [R * 8 + 1] + redS [R * 8 + 3] + redS [R * 8 + 5] + redS [R * 8 + 7];
            float T0 = redS2[R * 8 + 0] + redS2[R * 8 + 2] + redS2[R * 8 + 4] + redS2[R * 8 + 6];
            float T1 = redS2[R * 8 + 1] + redS2[R * 8 + 3] + redS2[R * 8 + 5] + redS2[R * 8 + 7];
            float mean0 = S0 * inv_gs, mean1 = S1 * inv_gs;
            float inv0 = rsqrtf(T0 * inv_gs - mean0 * mean0 + 1e-6f);
            float inv1 = rsqrtf(T1 * inv_gs - mean1 * mean1 + 1e-6f);
            size_t rowbase = (size_t)(brow + R) * N_DIM + bcol + wc * 16 + l15;
#pragma unroll
            for (int ni = 0; ni < 4; ++ni) {
                float mean = (ni < 2) ? mean0 : mean1;
                float inv  = (ni < 2) ? inv0  : inv1;
                float v = (acc[mi][ni][r] - mean) * inv + bv[ni];
                v = fminf(fmaxf(v, -2.0f), 2.0f);
                out[rowbase + ni * 64] = v;
            }
        }
}

extern "C" void kernel_launch(void* const* d_in, const int* in_sizes, int n_in,
                              void* d_out, int out_size, void* d_ws, size_t ws_size,
                              hipStream_t stream) {
    const float* x = (const float*)d_in[0];
    const float* W = (const float*)d_in[1];
    const float* b = (const float*)d_in[2];
    float* out = (float*)d_out;

    ushort_t* xb = (ushort_t*)d_ws;                       // 64 MB
    ushort_t* wb = xb + (size_t)M_DIM * K_DIM;            // +32 MB

    int n4x = M_DIM * K_DIM / 4;
    cvt_f32_bf16<<<(n4x + 255) / 256, 256, 0, stream>>>(
        (const float4*)x, xb, n4x);
    int n4w = N_DIM * K_DIM / 4;
    cvt_f32_bf16<<<(n4w + 255) / 256, 256, 0, stream>>>(
        (const float4*)W, wb, n4w);

    int grid = (M_DIM / BM) * (N_DIM / BN);               // 512 blocks
    gemm_gn_kernel<<<grid, 512, 0, stream>>>(xb, wb, b, out);
}